// Round 2
// 315.514 us; speedup vs baseline: 1.0181x; 1.0181x over previous
//
#include <hip/hip_runtime.h>

#define BATCH 16384
#define NFIELDS 26
#define FIELD_DIM 100000

// Round-5 single change (resubmit — previous round hit a GPU-broker timeout,
// kernel never ran): the kernel is scattered-load LATENCY bound, not
// bandwidth bound (effective gather BW ~0.24 TB/s << random-gather capability).
// Restructure gathers from 52 scalar (4B/lane) loads per 2-row wave into
// 15 float4 (16B/lane) loads per 4-row wave:
//   block0 (256B rows): 16 lanes/row -> 4 rows per instruction, 8 instrs
//   block1 (128B rows):  8 lanes/row, field-pairs on half-waves -> 4 instrs
//   block2 ( 64B rows):  4 lanes/row, 4 fields on quads         -> 3 instrs
// => ~7x fewer vmem instructions, ~10x more bytes in flight per wave.
// Indices staged in LDS (broadcast reads replace shfl-of-xi); partial sums
// reduced across half/quad replicas with shfl_xor; projections unchanged in
// math (sum-then-project, bias = 8*b1 + 10*b2) but read W as float4 from LDS
// with one shfl per k. __launch_bounds__(256,4): grid is 1024 blocks = 4/CU
// anyway, so take the 128-VGPR budget and keep all gathers in flight.

typedef float f32x4 __attribute__((ext_vector_type(4)));

__device__ __forceinline__ f32x4 ntload4(const float* p) {
    return __builtin_nontemporal_load((const f32x4*)p);
}

__global__ __launch_bounds__(256, 4) void mixdim_embbag_kernel(
    const int* __restrict__ x,
    const float* __restrict__ t0,
    const float* __restrict__ t1,
    const float* __restrict__ t2,
    const float* __restrict__ W1,
    const float* __restrict__ b1,
    const float* __restrict__ W2,
    const float* __restrict__ b2,
    float* __restrict__ out)
{
    __shared__ float ldsW1[32 * 64];        // W1T: [k][d], 8 KB
    __shared__ float ldsW2[16 * 64];        // W2T: [k][d], 4 KB
    __shared__ int   ldsX[16 * NFIELDS];    // this block's 16 rows of indices

    const int tid  = threadIdx.x;
    const int lane = tid & 63;
    const int wave = tid >> 6;

    // ---- one-time fills (coalesced global reads) ----
    #pragma unroll
    for (int i = 0; i < 8; ++i) {
        const int e = tid * 8 + i;                 // W1: 64*32 = 2048
        ldsW1[(e & 31) * 64 + (e >> 5)] = W1[e];   // [k][d]
    }
    #pragma unroll
    for (int i = 0; i < 4; ++i) {
        const int e = tid * 4 + i;                 // W2: 64*16 = 1024
        ldsW2[(e & 15) * 64 + (e >> 4)] = W2[e];
    }
    ldsX[tid] = x[blockIdx.x * (16 * NFIELDS) + tid];
    if (tid < 16 * NFIELDS - 256)
        ldsX[tid + 256] = x[blockIdx.x * (16 * NFIELDS) + tid + 256];

    __syncthreads();

    const int g = lane >> 4;                 // row within this wave's quad
    const int q = lane & 15;                 // float4 slot of the 64-dim output
    const int xbase = wave * 4 * NFIELDS;    // wave's rows in ldsX
    const int rowbase = blockIdx.x * 16 + wave * 4;

    f32x4 acc = {0.f, 0.f, 0.f, 0.f};

    // ---- block 0: fields 0..7, dim 64 (identity) — 4 rows per gather ----
    #pragma unroll
    for (int f = 0; f < 8; ++f) {
        const int idx = ldsX[xbase + g * NFIELDS + f] + f * FIELD_DIM;
        acc += ntload4(t0 + idx * 64 + q * 4);
    }

    // ---- block 1: fields 8..15, dim 32 — field pairs across half-waves ----
    float s1a[4] = {0.f, 0.f, 0.f, 0.f};
    {
        const int h  = lane >> 5;            // which field of the pair
        const int r1 = (lane >> 3) & 3;      // row
        const int c1 = lane & 7;             // float4 slot of 32 dims
        #pragma unroll
        for (int jj = 0; jj < 4; ++jj) {
            const int f = 8 + jj * 2 + h;
            const int idx = ldsX[xbase + r1 * NFIELDS + f] + (f - 8) * FIELD_DIM;
            const f32x4 v = ntload4(t1 + idx * 32 + c1 * 4);
            s1a[0] += v.x; s1a[1] += v.y; s1a[2] += v.z; s1a[3] += v.w;
        }
    }

    // ---- block 2: fields 16..25, dim 16 — 4 fields across quads ----
    float s2a[4] = {0.f, 0.f, 0.f, 0.f};
    {
        const int qd = lane >> 4;            // which field of the quad
        const int r2 = (lane >> 2) & 3;      // row
        const int c2 = lane & 3;             // float4 slot of 16 dims
        #pragma unroll
        for (int jj = 0; jj < 3; ++jj) {
            const int f = 16 + jj * 4 + qd;
            if (f < 26) {
                const int idx = ldsX[xbase + r2 * NFIELDS + f] + (f - 16) * FIELD_DIM;
                const f32x4 v = ntload4(t2 + idx * 16 + c2 * 4);
                s2a[0] += v.x; s2a[1] += v.y; s2a[2] += v.z; s2a[3] += v.w;
            }
        }
    }

    // ---- reduce the replicated halves/quads so full per-row sums exist ----
    #pragma unroll
    for (int c = 0; c < 4; ++c) {
        s1a[c] += __shfl_xor(s1a[c], 32);    // sum the two field-halves
        s2a[c] += __shfl_xor(s2a[c], 16);    // sum the four field-quads
        s2a[c] += __shfl_xor(s2a[c], 32);
    }

    // ---- projections: acc[d] += sum_k s[k] * W[d][k], W from LDS ----
    const f32x4* W1v = (const f32x4*)ldsW1;
    const f32x4* W2v = (const f32x4*)ldsW2;
    #pragma unroll
    for (int k = 0; k < 32; ++k) {
        const float v = __shfl(s1a[k & 3], g * 8 + (k >> 2));
        acc += W1v[k * 16 + q] * v;
    }
    #pragma unroll
    for (int k = 0; k < 16; ++k) {
        const float v = __shfl(s2a[k & 3], g * 4 + (k >> 2));
        acc += W2v[k * 16 + q] * v;
    }

    // ---- bias (8 field-projections in block1, 10 in block2) + store ----
    const f32x4 bias = ((const f32x4*)b1)[q] * 8.0f + ((const f32x4*)b2)[q] * 10.0f;
    const int row = rowbase + g;
    *(f32x4*)(out + row * 64 + q * 4) = acc + bias;
}

extern "C" void kernel_launch(void* const* d_in, const int* in_sizes, int n_in,
                              void* d_out, int out_size, void* d_ws, size_t ws_size,
                              hipStream_t stream) {
    const int*   x  = (const int*)  d_in[0];
    const float* t0 = (const float*)d_in[1];
    const float* t1 = (const float*)d_in[2];
    const float* t2 = (const float*)d_in[3];
    const float* W1 = (const float*)d_in[4];
    const float* b1 = (const float*)d_in[5];
    const float* W2 = (const float*)d_in[6];
    const float* b2 = (const float*)d_in[7];
    float* out = (float*)d_out;

    dim3 grid(BATCH / 16);   // 4 waves/block, 4 rows/wave
    dim3 block(256);
    hipLaunchKernelGGL(mixdim_embbag_kernel, grid, block, 0, stream,
                       x, t0, t1, t2, W1, b1, W2, b2, out);
}